// Round 1
// baseline (462.285 us; speedup 1.0000x reference)
//
#include <hip/hip_runtime.h>
#include <hip/hip_bf16.h>

#define T_TOK 4096
#define DIM   768
#define FF    3072
#define NE    8

typedef __attribute__((ext_vector_type(8))) short bf16x8;
typedef __attribute__((ext_vector_type(4))) short bf16x4;
typedef __attribute__((ext_vector_type(4))) float f32x4;

__device__ __forceinline__ unsigned short f2bf(float f) {
    union { float f; unsigned int u; } v; v.f = f;
    unsigned int u = v.u;
    u += 0x7FFFu + ((u >> 16) & 1u);   // round-to-nearest-even
    return (unsigned short)(u >> 16);
}

__device__ __forceinline__ bf16x8 pack8(f32x4 a, f32x4 b) {
    bf16x8 r;
    r[0] = (short)f2bf(a[0]); r[1] = (short)f2bf(a[1]);
    r[2] = (short)f2bf(a[2]); r[3] = (short)f2bf(a[3]);
    r[4] = (short)f2bf(b[0]); r[5] = (short)f2bf(b[1]);
    r[6] = (short)f2bf(b[2]); r[7] = (short)f2bf(b[3]);
    return r;
}

// ---------------- Router: one wave per token ----------------
__global__ __launch_bounds__(256) void k_router(
    const float* __restrict__ x, const float* __restrict__ wr,
    float* __restrict__ out_logits, float* __restrict__ out_eidx,
    float* __restrict__ probs, int* __restrict__ counts, int* __restrict__ bucket)
{
    int tok  = (blockIdx.x * 256 + threadIdx.x) >> 6;
    int lane = threadIdx.x & 63;
    if (tok >= T_TOK) return;
    const float* xr = x + (size_t)tok * DIM;
    float acc[NE];
    #pragma unroll
    for (int e = 0; e < NE; e++) acc[e] = 0.f;
    #pragma unroll
    for (int j = 0; j < DIM / 64; j++) {
        int d = j * 64 + lane;                 // coalesced
        float xv = xr[d];
        const float* wrow = wr + (size_t)d * NE;
        #pragma unroll
        for (int e = 0; e < NE; e++) acc[e] += xv * wrow[e];
    }
    #pragma unroll
    for (int e = 0; e < NE; e++) {
        #pragma unroll
        for (int off = 32; off >= 1; off >>= 1)
            acc[e] += __shfl_xor(acc[e], off);
    }
    if (lane == 0) {
        float mx = acc[0]; int mi = 0;
        #pragma unroll
        for (int e = 1; e < NE; e++) if (acc[e] > mx) { mx = acc[e]; mi = e; }
        float se = 0.f;
        #pragma unroll
        for (int e = 0; e < NE; e++) se += __expf(acc[e] - mx);
        #pragma unroll
        for (int e = 0; e < NE; e++) out_logits[(size_t)tok * NE + e] = acc[e];
        out_eidx[tok] = (float)mi;
        probs[tok] = 1.f / se;
        int pos = atomicAdd(&counts[mi], 1);
        bucket[mi * T_TOK + pos] = tok;
    }
}

// ---------------- Compact: offsets + sorted token list ----------------
__global__ void k_compact(const int* __restrict__ counts, int* __restrict__ offsets,
                          const int* __restrict__ bucket, int* __restrict__ sorted)
{
    __shared__ int soff[NE + 1];
    if (threadIdx.x == 0) {
        int s = 0;
        for (int e = 0; e < NE; e++) { soff[e] = s; s += counts[e]; }
        soff[NE] = s;
        for (int e = 0; e <= NE; e++) offsets[e] = soff[e];
    }
    __syncthreads();
    for (int e = 0; e < NE; e++) {
        int c = counts[e], o = soff[e];
        for (int i = threadIdx.x; i < c; i += blockDim.x)
            sorted[o + i] = bucket[e * T_TOK + i];
    }
}

// ---------------- Gather: pack X rows (sorted order) to bf16 ----------------
__global__ __launch_bounds__(256) void k_gather(
    const float* __restrict__ x, const int* __restrict__ sorted,
    unsigned short* __restrict__ Xg)
{
    int g0 = (blockIdx.x * 256 + threadIdx.x) * 8;      // 8 elems / thread
    if (g0 >= T_TOK * DIM) return;
    int row = g0 / DIM, col = g0 - row * DIM;
    const float* src = x + (size_t)sorted[row] * DIM + col;
    f32x4 a = *(const f32x4*)(src);
    f32x4 b = *(const f32x4*)(src + 4);
    *(bf16x8*)(Xg + (size_t)row * DIM + col) = pack8(a, b);
}

// ---------------- GEMM1: H = relu(Xg @ w1[e] + b1[e]), 128x128 tiles ----------------
__global__ __launch_bounds__(256) void k_gemm1(
    const unsigned short* __restrict__ Xg, const float* __restrict__ w1,
    const float* __restrict__ b1, const int* __restrict__ counts,
    const int* __restrict__ offsets, unsigned short* __restrict__ Hbuf)
{
    const int e   = blockIdx.y >> 5;
    const int ti  = blockIdx.y & 31;
    const int cnt = counts[e];
    if (ti * 128 >= cnt) return;
    const int n0    = blockIdx.x * 128;
    const int off   = offsets[e];
    const int rbase = ti * 128;
    const int rmax  = cnt - rbase - 1;
    const int tid   = threadIdx.x;
    const int lane  = tid & 63;
    const int wave  = tid >> 6;
    const int wm = wave >> 1, wn = wave & 1;

    __shared__ unsigned short As[128][40];   // A[m][k], pad 40
    __shared__ unsigned short Bs[128][40];   // B^T[n][k], pad 40

    const float* w1e = w1 + (size_t)e * DIM * FF;
    f32x4 acc[4][4];
    #pragma unroll
    for (int i = 0; i < 4; i++)
        #pragma unroll
        for (int j = 0; j < 4; j++) acc[i][j] = (f32x4)0.f;

    const int arow = tid >> 1, aseg = tid & 1;       // A: 2 threads/row
    const int kb = tid >> 5, nb = tid & 31;          // B: 4x4 transpose blocks

    for (int k0 = 0; k0 < DIM; k0 += 32) {
        __syncthreads();
        {   // A tile: 128 rows x 32 k (bf16 source, direct copy)
            int re = (arow <= rmax) ? arow : 0;
            const unsigned short* src = Xg + (size_t)(off + rbase + re) * DIM + k0 + aseg * 16;
            bf16x8 h0 = *(const bf16x8*)(src);
            bf16x8 h1 = *(const bf16x8*)(src + 8);
            *(bf16x8*)&As[arow][aseg * 16]     = h0;
            *(bf16x8*)&As[arow][aseg * 16 + 8] = h1;
        }
        {   // B tile: 32 k x 128 n, fp32 -> bf16, transpose into Bs[n][k]
            const float* src = w1e + (size_t)(k0 + kb * 4) * FF + n0 + nb * 4;
            f32x4 r0 = *(const f32x4*)(src);
            f32x4 r1 = *(const f32x4*)(src + FF);
            f32x4 r2 = *(const f32x4*)(src + 2 * FF);
            f32x4 r3 = *(const f32x4*)(src + 3 * FF);
            #pragma unroll
            for (int j = 0; j < 4; j++) {
                bf16x4 c;
                c[0] = (short)f2bf(r0[j]); c[1] = (short)f2bf(r1[j]);
                c[2] = (short)f2bf(r2[j]); c[3] = (short)f2bf(r3[j]);
                *(bf16x4*)&Bs[nb * 4 + j][kb * 4] = c;
            }
        }
        __syncthreads();
        const int lrow = lane & 15, kq = lane >> 4;
        bf16x8 af[4], bfr[4];
        #pragma unroll
        for (int i = 0; i < 4; i++)
            af[i] = *(const bf16x8*)&As[wm * 64 + i * 16 + lrow][kq * 8];
        #pragma unroll
        for (int i = 0; i < 4; i++)
            bfr[i] = *(const bf16x8*)&Bs[wn * 64 + i * 16 + lrow][kq * 8];
        #pragma unroll
        for (int mi = 0; mi < 4; mi++)
            #pragma unroll
            for (int ni = 0; ni < 4; ni++)
                acc[mi][ni] = __builtin_amdgcn_mfma_f32_16x16x32_bf16(
                    af[mi], bfr[ni], acc[mi][ni], 0, 0, 0);
    }

    // epilogue: bias + relu -> Hbuf (bf16), C/D layout col=lane&15 row=quad*4+r
    const int lrow = lane & 15, quad = lane >> 4;
    #pragma unroll
    for (int ni = 0; ni < 4; ni++) {
        int gn = n0 + wn * 64 + ni * 16 + lrow;
        float bias = b1[e * FF + gn];
        #pragma unroll
        for (int mi = 0; mi < 4; mi++) {
            f32x4 v = acc[mi][ni];
            #pragma unroll
            for (int r = 0; r < 4; r++) {
                int ml = wm * 64 + mi * 16 + quad * 4 + r;
                if (rbase + ml < cnt) {
                    float h = v[r] + bias;
                    h = h > 0.f ? h : 0.f;
                    Hbuf[(size_t)(off + rbase + ml) * FF + gn] = f2bf(h);
                }
            }
        }
    }
}

// ---------------- GEMM2: out = (H @ w2[e] + b2[e]) * prob, scatter. 128x64 tiles ----------------
__global__ __launch_bounds__(128) void k_gemm2(
    const unsigned short* __restrict__ Hbuf, const float* __restrict__ w2,
    const float* __restrict__ b2, const int* __restrict__ sorted,
    const int* __restrict__ counts, const int* __restrict__ offsets,
    const float* __restrict__ probs, float* __restrict__ outh)
{
    const int e   = blockIdx.y >> 5;
    const int ti  = blockIdx.y & 31;
    const int cnt = counts[e];
    if (ti * 128 >= cnt) return;
    const int n0    = blockIdx.x * 64;
    const int off   = offsets[e];
    const int rbase = ti * 128;
    const int rmax  = cnt - rbase - 1;
    const int tid   = threadIdx.x;
    const int lane  = tid & 63;
    const int wm    = tid >> 6;       // wave 0: rows 0-63, wave 1: rows 64-127

    __shared__ unsigned short As[128][40];
    __shared__ unsigned short Bs[64][40];
    __shared__ int   s_tok[128];
    __shared__ float s_prob[128];

    {   // token ids + probs for scatter
        int r = rbase + tid;
        int tk = sorted[off + ((r < cnt) ? r : rbase)];
        s_tok[tid]  = tk;
        s_prob[tid] = probs[tk];
    }

    const float* w2e = w2 + (size_t)e * FF * DIM;
    f32x4 acc[4][4];
    #pragma unroll
    for (int i = 0; i < 4; i++)
        #pragma unroll
        for (int j = 0; j < 4; j++) acc[i][j] = (f32x4)0.f;

    const int kb = tid >> 4, nb = tid & 15;   // B: 8 kb x 16 nb (4x4 blocks)

    for (int k0 = 0; k0 < FF; k0 += 32) {
        __syncthreads();
        {   // A tile: 128 rows x 32 k from Hbuf (1 thread/row, 64 B)
            int re = (tid <= rmax) ? tid : 0;
            const unsigned short* src = Hbuf + (size_t)(off + rbase + re) * FF + k0;
            bf16x8 h0 = *(const bf16x8*)(src);
            bf16x8 h1 = *(const bf16x8*)(src + 8);
            bf16x8 h2 = *(const bf16x8*)(src + 16);
            bf16x8 h3 = *(const bf16x8*)(src + 24);
            *(bf16x8*)&As[tid][0]  = h0;
            *(bf16x8*)&As[tid][8]  = h1;
            *(bf16x8*)&As[tid][16] = h2;
            *(bf16x8*)&As[tid][24] = h3;
        }
        {   // B tile: 32 k x 64 n from w2, transpose into Bs[n][k]
            const float* src = w2e + (size_t)(k0 + kb * 4) * DIM + n0 + nb * 4;
            f32x4 r0 = *(const f32x4*)(src);
            f32x4 r1 = *(const f32x4*)(src + DIM);
            f32x4 r2 = *(const f32x4*)(src + 2 * DIM);
            f32x4 r3 = *(const f32x4*)(src + 3 * DIM);
            #pragma unroll
            for (int j = 0; j < 4; j++) {
                bf16x4 c;
                c[0] = (short)f2bf(r0[j]); c[1] = (short)f2bf(r1[j]);
                c[2] = (short)f2bf(r2[j]); c[3] = (short)f2bf(r3[j]);
                *(bf16x4*)&Bs[nb * 4 + j][kb * 4] = c;
            }
        }
        __syncthreads();
        const int lrow = lane & 15, kq = lane >> 4;
        bf16x8 af[4], bfr[4];
        #pragma unroll
        for (int i = 0; i < 4; i++)
            af[i] = *(const bf16x8*)&As[wm * 64 + i * 16 + lrow][kq * 8];
        #pragma unroll
        for (int i = 0; i < 4; i++)
            bfr[i] = *(const bf16x8*)&Bs[i * 16 + lrow][kq * 8];
        #pragma unroll
        for (int mi = 0; mi < 4; mi++)
            #pragma unroll
            for (int ni = 0; ni < 4; ni++)
                acc[mi][ni] = __builtin_amdgcn_mfma_f32_16x16x32_bf16(
                    af[mi], bfr[ni], acc[mi][ni], 0, 0, 0);
    }

    // epilogue: (acc + b2) * prob, scatter by token id
    const int lrow = lane & 15, quad = lane >> 4;
    #pragma unroll
    for (int ni = 0; ni < 4; ni++) {
        int gn = n0 + ni * 16 + lrow;
        float bias = b2[e * DIM + gn];
        #pragma unroll
        for (int mi = 0; mi < 4; mi++) {
            f32x4 v = acc[mi][ni];
            #pragma unroll
            for (int r = 0; r < 4; r++) {
                int ml = wm * 64 + mi * 16 + quad * 4 + r;
                if (rbase + ml < cnt) {
                    outh[(size_t)s_tok[ml] * DIM + gn] = (v[r] + bias) * s_prob[ml];
                }
            }
        }
    }
}

extern "C" void kernel_launch(void* const* d_in, const int* in_sizes, int n_in,
                              void* d_out, int out_size, void* d_ws, size_t ws_size,
                              hipStream_t stream) {
    (void)in_sizes; (void)n_in; (void)out_size; (void)ws_size;
    const float* x  = (const float*)d_in[0];
    const float* wr = (const float*)d_in[1];
    const float* w1 = (const float*)d_in[2];
    const float* b1 = (const float*)d_in[3];
    const float* w2 = (const float*)d_in[4];
    const float* b2 = (const float*)d_in[5];

    float* out_hidden = (float*)d_out;                        // [T, D]
    float* out_logits = out_hidden + (size_t)T_TOK * DIM;     // [T, E]
    float* out_eidx   = out_logits + (size_t)T_TOK * NE;      // [T]

    char* ws = (char*)d_ws;
    int*   counts  = (int*)(ws + 0);            // 8 ints
    int*   offsets = (int*)(ws + 64);           // 9 ints
    float* probs   = (float*)(ws + 128);        // T floats
    int*   sorted  = (int*)(ws + 16512);        // T ints
    int*   bucket  = (int*)(ws + 32896);        // E*T ints
    unsigned short* Xg   = (unsigned short*)(ws + 163968);    // T*DIM bf16
    unsigned short* Hbuf = (unsigned short*)(ws + 6455424);   // T*FF bf16

    hipMemsetAsync(counts, 0, 32, stream);
    k_router<<<dim3(T_TOK / 4), dim3(256), 0, stream>>>(
        x, wr, out_logits, out_eidx, probs, counts, bucket);
    k_compact<<<dim3(1), dim3(256), 0, stream>>>(counts, offsets, bucket, sorted);
    k_gather<<<dim3((T_TOK * DIM / 8 + 255) / 256), dim3(256), 0, stream>>>(x, sorted, Xg);
    k_gemm1<<<dim3(FF / 128, NE * 32), dim3(256), 0, stream>>>(
        Xg, w1, b1, counts, offsets, Hbuf);
    k_gemm2<<<dim3(DIM / 64, NE * 32), dim3(128), 0, stream>>>(
        Hbuf, w2, b2, sorted, counts, offsets, probs, out_hidden);
}

// Round 2
// 413.031 us; speedup vs baseline: 1.1192x; 1.1192x over previous
//
#include <hip/hip_runtime.h>
#include <hip/hip_bf16.h>

#define T_TOK 4096
#define DIM   768
#define FF    3072
#define NE    8

typedef __attribute__((ext_vector_type(8))) short bf16x8;
typedef __attribute__((ext_vector_type(4))) short bf16x4;
typedef __attribute__((ext_vector_type(4))) float f32x4;
typedef __attribute__((ext_vector_type(2))) float f32x2;

__device__ __forceinline__ unsigned short f2bf(float f) {
    union { float f; unsigned int u; } v; v.f = f;
    unsigned int u = v.u;
    u += 0x7FFFu + ((u >> 16) & 1u);   // round-to-nearest-even
    return (unsigned short)(u >> 16);
}

__device__ __forceinline__ bf16x8 pack8(f32x4 a, f32x4 b) {
    bf16x8 r;
    r[0] = (short)f2bf(a[0]); r[1] = (short)f2bf(a[1]);
    r[2] = (short)f2bf(a[2]); r[3] = (short)f2bf(a[3]);
    r[4] = (short)f2bf(b[0]); r[5] = (short)f2bf(b[1]);
    r[6] = (short)f2bf(b[2]); r[7] = (short)f2bf(b[3]);
    return r;
}

// ---------------- Router: one wave per token ----------------
__global__ __launch_bounds__(256) void k_router(
    const float* __restrict__ x, const float* __restrict__ wr,
    float* __restrict__ out_logits, float* __restrict__ out_eidx,
    float* __restrict__ probs, int* __restrict__ counts, int* __restrict__ bucket)
{
    int tok  = (blockIdx.x * 256 + threadIdx.x) >> 6;
    int lane = threadIdx.x & 63;
    if (tok >= T_TOK) return;
    const float* xr = x + (size_t)tok * DIM;
    float acc[NE];
    #pragma unroll
    for (int e = 0; e < NE; e++) acc[e] = 0.f;
    #pragma unroll
    for (int j = 0; j < DIM / 64; j++) {
        int d = j * 64 + lane;
        float xv = xr[d];
        const float* wrow = wr + (size_t)d * NE;
        #pragma unroll
        for (int e = 0; e < NE; e++) acc[e] += xv * wrow[e];
    }
    #pragma unroll
    for (int e = 0; e < NE; e++) {
        #pragma unroll
        for (int off = 32; off >= 1; off >>= 1)
            acc[e] += __shfl_xor(acc[e], off);
    }
    if (lane == 0) {
        float mx = acc[0]; int mi = 0;
        #pragma unroll
        for (int e = 1; e < NE; e++) if (acc[e] > mx) { mx = acc[e]; mi = e; }
        float se = 0.f;
        #pragma unroll
        for (int e = 0; e < NE; e++) se += __expf(acc[e] - mx);
        #pragma unroll
        for (int e = 0; e < NE; e++) out_logits[(size_t)tok * NE + e] = acc[e];
        out_eidx[tok] = (float)mi;
        probs[tok] = 1.f / se;
        int pos = atomicAdd(&counts[mi], 1);
        bucket[mi * T_TOK + pos] = tok;
    }
}

// ---------------- Compact ----------------
__global__ void k_compact(const int* __restrict__ counts, int* __restrict__ offsets,
                          const int* __restrict__ bucket, int* __restrict__ sorted)
{
    __shared__ int soff[NE + 1];
    if (threadIdx.x == 0) {
        int s = 0;
        for (int e = 0; e < NE; e++) { soff[e] = s; s += counts[e]; }
        soff[NE] = s;
        for (int e = 0; e <= NE; e++) offsets[e] = soff[e];
    }
    __syncthreads();
    for (int e = 0; e < NE; e++) {
        int c = counts[e], o = soff[e];
        for (int i = threadIdx.x; i < c; i += blockDim.x)
            sorted[o + i] = bucket[e * T_TOK + i];
    }
}

// ---------------- Gather ----------------
__global__ __launch_bounds__(256) void k_gather(
    const float* __restrict__ x, const int* __restrict__ sorted,
    unsigned short* __restrict__ Xg)
{
    int g0 = (blockIdx.x * 256 + threadIdx.x) * 8;
    if (g0 >= T_TOK * DIM) return;
    int row = g0 / DIM, col = g0 - row * DIM;
    const float* src = x + (size_t)sorted[row] * DIM + col;
    f32x4 a = *(const f32x4*)(src);
    f32x4 b = *(const f32x4*)(src + 4);
    *(bf16x8*)(Xg + (size_t)row * DIM + col) = pack8(a, b);
}

// ---------------- GEMM1: H = relu(Xg @ w1[e] + b1), 128x128, BK=64, pipelined ----------------
__global__ __launch_bounds__(256, 3) void k_gemm1(
    const unsigned short* __restrict__ Xg, const float* __restrict__ w1,
    const float* __restrict__ b1, const int* __restrict__ counts,
    const int* __restrict__ offsets, unsigned short* __restrict__ Hbuf)
{
    const int e   = blockIdx.y >> 5;
    const int ti  = blockIdx.y & 31;
    const int cnt = counts[e];
    if (ti * 128 >= cnt) return;
    const int n0    = blockIdx.x * 128;
    const int off   = offsets[e];
    const int rbase = ti * 128;
    const int rmax  = cnt - rbase - 1;
    const int tid   = threadIdx.x;
    const int lane  = tid & 63;
    const int wave  = tid >> 6;
    const int wm = wave >> 1, wn = wave & 1;

    __shared__ unsigned short As[128][72];   // A[m][k]
    __shared__ unsigned short Bs[128][72];   // B^T[n][k]

    const float* w1e = w1 + (size_t)e * DIM * FF;
    f32x4 acc[4][4];
    #pragma unroll
    for (int i = 0; i < 4; i++)
        #pragma unroll
        for (int j = 0; j < 4; j++) acc[i][j] = (f32x4)0.f;

    // A staging: 1 thread covers 32 contiguous k of one row
    const int arow = tid >> 1, aseg = tid & 1;
    const int are  = (arow <= rmax) ? arow : 0;
    const unsigned short* abase = Xg + (size_t)(off + rbase + are) * DIM + aseg * 32;
    // B staging: thread covers 8 k-rows x 4 n
    const int kb = tid >> 5, nb = tid & 31;
    const float* bbase = w1e + (size_t)kb * 8 * FF + n0 + nb * 4;

    bf16x8 aR[4];
    f32x4  bR[8];
    #pragma unroll
    for (int j = 0; j < 4; j++) aR[j] = *(const bf16x8*)(abase + j * 8);
    #pragma unroll
    for (int r = 0; r < 8; r++) bR[r] = *(const f32x4*)(bbase + (size_t)r * FF);

    const int lrow = lane & 15, kq = lane >> 4;

    for (int it = 0; it < DIM / 64; ++it) {
        __syncthreads();
        #pragma unroll
        for (int j = 0; j < 4; j++)
            *(bf16x8*)&As[arow][aseg * 32 + j * 8] = aR[j];
        #pragma unroll
        for (int j = 0; j < 4; j++) {
            bf16x8 c;
            #pragma unroll
            for (int r = 0; r < 8; r++) c[r] = (short)f2bf(bR[r][j]);
            *(bf16x8*)&Bs[nb * 4 + j][kb * 8] = c;
        }
        __syncthreads();
        if (it + 1 < DIM / 64) {
            const unsigned short* an = abase + (it + 1) * 64;
            #pragma unroll
            for (int j = 0; j < 4; j++) aR[j] = *(const bf16x8*)(an + j * 8);
            const float* bn = bbase + (size_t)(it + 1) * 64 * FF;
            #pragma unroll
            for (int r = 0; r < 8; r++) bR[r] = *(const f32x4*)(bn + (size_t)r * FF);
        }
        #pragma unroll
        for (int ks = 0; ks < 2; ks++) {
            bf16x8 af[4], bfr[4];
            #pragma unroll
            for (int i = 0; i < 4; i++)
                af[i] = *(const bf16x8*)&As[wm * 64 + i * 16 + lrow][ks * 32 + kq * 8];
            #pragma unroll
            for (int i = 0; i < 4; i++)
                bfr[i] = *(const bf16x8*)&Bs[wn * 64 + i * 16 + lrow][ks * 32 + kq * 8];
            #pragma unroll
            for (int mi = 0; mi < 4; mi++)
                #pragma unroll
                for (int ni = 0; ni < 4; ni++)
                    acc[mi][ni] = __builtin_amdgcn_mfma_f32_16x16x32_bf16(
                        af[mi], bfr[ni], acc[mi][ni], 0, 0, 0);
        }
    }

    const int quad = lane >> 4;
    #pragma unroll
    for (int ni = 0; ni < 4; ni++) {
        int gn = n0 + wn * 64 + ni * 16 + lrow;
        float bias = b1[e * FF + gn];
        #pragma unroll
        for (int mi = 0; mi < 4; mi++) {
            f32x4 v = acc[mi][ni];
            #pragma unroll
            for (int r = 0; r < 4; r++) {
                int ml = wm * 64 + mi * 16 + quad * 4 + r;
                if (rbase + ml < cnt) {
                    float h = v[r] + bias;
                    h = h > 0.f ? h : 0.f;
                    Hbuf[(size_t)(off + rbase + ml) * FF + gn] = f2bf(h);
                }
            }
        }
    }
}

// ---------------- GEMM2: out = (H @ w2[e] + b2) * prob, 128x64, BK=64, pipelined ----------------
__global__ __launch_bounds__(256, 4) void k_gemm2(
    const unsigned short* __restrict__ Hbuf, const float* __restrict__ w2,
    const float* __restrict__ b2, const int* __restrict__ sorted,
    const int* __restrict__ counts, const int* __restrict__ offsets,
    const float* __restrict__ probs, float* __restrict__ outh)
{
    const int e   = blockIdx.y >> 5;
    const int ti  = blockIdx.y & 31;
    const int cnt = counts[e];
    if (ti * 128 >= cnt) return;
    const int n0    = blockIdx.x * 64;
    const int off   = offsets[e];
    const int rbase = ti * 128;
    const int rmax  = cnt - rbase - 1;
    const int tid   = threadIdx.x;
    const int lane  = tid & 63;
    const int wave  = tid >> 6;
    const int wm = wave >> 1, wn = wave & 1;   // wave computes 64 rows x 32 cols

    __shared__ unsigned short As[128][72];
    __shared__ unsigned short Bs[64][72];
    __shared__ int   s_tok[128];
    __shared__ float s_prob[128];

    if (tid < 128) {
        int r = rbase + tid;
        int tk = sorted[off + ((r < cnt) ? r : rbase)];
        s_tok[tid]  = tk;
        s_prob[tid] = probs[tk];
    }

    const float* w2e = w2 + (size_t)e * FF * DIM;
    f32x4 acc[4][2];
    #pragma unroll
    for (int i = 0; i < 4; i++)
        #pragma unroll
        for (int j = 0; j < 2; j++) acc[i][j] = (f32x4)0.f;

    // A staging: 1 thread = 32 contiguous k of one row
    const int arow = tid >> 1, aseg = tid & 1;
    const int are  = (arow <= rmax) ? arow : 0;
    const unsigned short* abase = Hbuf + (size_t)(off + rbase + are) * FF + aseg * 32;
    // B staging: thread covers 8 k-rows x 2 n
    const int kb = tid >> 5, nb = tid & 31;
    const float* bbase = w2e + (size_t)kb * 8 * DIM + n0 + nb * 2;

    bf16x8 aR[4];
    f32x2  bR[8];
    #pragma unroll
    for (int j = 0; j < 4; j++) aR[j] = *(const bf16x8*)(abase + j * 8);
    #pragma unroll
    for (int r = 0; r < 8; r++) bR[r] = *(const f32x2*)(bbase + (size_t)r * DIM);

    const int lrow = lane & 15, kq = lane >> 4;

    for (int it = 0; it < FF / 64; ++it) {
        __syncthreads();
        #pragma unroll
        for (int j = 0; j < 4; j++)
            *(bf16x8*)&As[arow][aseg * 32 + j * 8] = aR[j];
        {
            bf16x8 c0, c1;
            #pragma unroll
            for (int r = 0; r < 8; r++) { c0[r] = (short)f2bf(bR[r][0]); c1[r] = (short)f2bf(bR[r][1]); }
            *(bf16x8*)&Bs[nb * 2 + 0][kb * 8] = c0;
            *(bf16x8*)&Bs[nb * 2 + 1][kb * 8] = c1;
        }
        __syncthreads();
        if (it + 1 < FF / 64) {
            const unsigned short* an = abase + (it + 1) * 64;
            #pragma unroll
            for (int j = 0; j < 4; j++) aR[j] = *(const bf16x8*)(an + j * 8);
            const float* bn = bbase + (size_t)(it + 1) * 64 * DIM;
            #pragma unroll
            for (int r = 0; r < 8; r++) bR[r] = *(const f32x2*)(bn + (size_t)r * DIM);
        }
        #pragma unroll
        for (int ks = 0; ks < 2; ks++) {
            bf16x8 af[4], bfr[2];
            #pragma unroll
            for (int i = 0; i < 4; i++)
                af[i] = *(const bf16x8*)&As[wm * 64 + i * 16 + lrow][ks * 32 + kq * 8];
            #pragma unroll
            for (int i = 0; i < 2; i++)
                bfr[i] = *(const bf16x8*)&Bs[wn * 32 + i * 16 + lrow][ks * 32 + kq * 8];
            #pragma unroll
            for (int mi = 0; mi < 4; mi++)
                #pragma unroll
                for (int ni = 0; ni < 2; ni++)
                    acc[mi][ni] = __builtin_amdgcn_mfma_f32_16x16x32_bf16(
                        af[mi], bfr[ni], acc[mi][ni], 0, 0, 0);
        }
    }

    const int quad = lane >> 4;
    #pragma unroll
    for (int ni = 0; ni < 2; ni++) {
        int gn = n0 + wn * 32 + ni * 16 + lrow;
        float bias = b2[e * DIM + gn];
        #pragma unroll
        for (int mi = 0; mi < 4; mi++) {
            f32x4 v = acc[mi][ni];
            #pragma unroll
            for (int r = 0; r < 4; r++) {
                int ml = wm * 64 + mi * 16 + quad * 4 + r;
                if (rbase + ml < cnt) {
                    outh[(size_t)s_tok[ml] * DIM + gn] = (v[r] + bias) * s_prob[ml];
                }
            }
        }
    }
}

extern "C" void kernel_launch(void* const* d_in, const int* in_sizes, int n_in,
                              void* d_out, int out_size, void* d_ws, size_t ws_size,
                              hipStream_t stream) {
    (void)in_sizes; (void)n_in; (void)out_size; (void)ws_size;
    const float* x  = (const float*)d_in[0];
    const float* wr = (const float*)d_in[1];
    const float* w1 = (const float*)d_in[2];
    const float* b1 = (const float*)d_in[3];
    const float* w2 = (const float*)d_in[4];
    const float* b2 = (const float*)d_in[5];

    float* out_hidden = (float*)d_out;                        // [T, D]
    float* out_logits = out_hidden + (size_t)T_TOK * DIM;     // [T, E]
    float* out_eidx   = out_logits + (size_t)T_TOK * NE;      // [T]

    char* ws = (char*)d_ws;
    int*   counts  = (int*)(ws + 0);
    int*   offsets = (int*)(ws + 64);
    float* probs   = (float*)(ws + 128);
    int*   sorted  = (int*)(ws + 16512);
    int*   bucket  = (int*)(ws + 32896);
    unsigned short* Xg   = (unsigned short*)(ws + 163968);
    unsigned short* Hbuf = (unsigned short*)(ws + 6455424);

    hipMemsetAsync(counts, 0, 32, stream);
    k_router<<<dim3(T_TOK / 4), dim3(256), 0, stream>>>(
        x, wr, out_logits, out_eidx, probs, counts, bucket);
    k_compact<<<dim3(1), dim3(256), 0, stream>>>(counts, offsets, bucket, sorted);
    k_gather<<<dim3((T_TOK * DIM / 8 + 255) / 256), dim3(256), 0, stream>>>(x, sorted, Xg);
    k_gemm1<<<dim3(FF / 128, NE * 32), dim3(256), 0, stream>>>(
        Xg, w1, b1, counts, offsets, Hbuf);
    k_gemm2<<<dim3(DIM / 64, NE * 32), dim3(256), 0, stream>>>(
        Hbuf, w2, b2, sorted, counts, offsets, probs, out_hidden);
}

// Round 3
// 390.673 us; speedup vs baseline: 1.1833x; 1.0572x over previous
//
#include <hip/hip_runtime.h>
#include <hip/hip_bf16.h>

#define T_TOK 4096
#define DIM   768
#define FF    3072
#define NE    8

typedef __attribute__((ext_vector_type(8))) short bf16x8;
typedef __attribute__((ext_vector_type(4))) short bf16x4;
typedef __attribute__((ext_vector_type(4))) float f32x4;
typedef __attribute__((ext_vector_type(2))) float f32x2;

typedef __attribute__((address_space(1))) void gvoid_t;
typedef __attribute__((address_space(3))) void lvoid_t;

__device__ __forceinline__ void g2l16(const void* g, void* l) {
    // async global->LDS, 16B per lane; LDS dest must be wave-uniform base
    __builtin_amdgcn_global_load_lds((gvoid_t*)(void*)g, (lvoid_t*)l, 16, 0, 0);
}

__device__ __forceinline__ unsigned short f2bf(float f) {
    union { float f; unsigned int u; } v; v.f = f;
    unsigned int u = v.u;
    u += 0x7FFFu + ((u >> 16) & 1u);   // round-to-nearest-even
    return (unsigned short)(u >> 16);
}

__device__ __forceinline__ bf16x8 pack8(f32x4 a, f32x4 b) {
    bf16x8 r;
    r[0] = (short)f2bf(a[0]); r[1] = (short)f2bf(a[1]);
    r[2] = (short)f2bf(a[2]); r[3] = (short)f2bf(a[3]);
    r[4] = (short)f2bf(b[0]); r[5] = (short)f2bf(b[1]);
    r[6] = (short)f2bf(b[2]); r[7] = (short)f2bf(b[3]);
    return r;
}

// ---------------- Router: one wave per token ----------------
__global__ __launch_bounds__(256) void k_router(
    const float* __restrict__ x, const float* __restrict__ wr,
    float* __restrict__ out_logits, float* __restrict__ out_eidx,
    float* __restrict__ probs, int* __restrict__ eidx_i,
    int* __restrict__ counts, int* __restrict__ bucket)
{
    int tok  = (blockIdx.x * 256 + threadIdx.x) >> 6;
    int lane = threadIdx.x & 63;
    if (tok >= T_TOK) return;
    const float* xr = x + (size_t)tok * DIM;
    float acc[NE];
    #pragma unroll
    for (int e = 0; e < NE; e++) acc[e] = 0.f;
    #pragma unroll
    for (int j = 0; j < DIM / 64; j++) {
        int d = j * 64 + lane;
        float xv = xr[d];
        const float* wrow = wr + (size_t)d * NE;
        #pragma unroll
        for (int e = 0; e < NE; e++) acc[e] += xv * wrow[e];
    }
    #pragma unroll
    for (int e = 0; e < NE; e++) {
        #pragma unroll
        for (int off = 32; off >= 1; off >>= 1)
            acc[e] += __shfl_xor(acc[e], off);
    }
    if (lane == 0) {
        float mx = acc[0]; int mi = 0;
        #pragma unroll
        for (int e = 1; e < NE; e++) if (acc[e] > mx) { mx = acc[e]; mi = e; }
        float se = 0.f;
        #pragma unroll
        for (int e = 0; e < NE; e++) se += __expf(acc[e] - mx);
        #pragma unroll
        for (int e = 0; e < NE; e++) out_logits[(size_t)tok * NE + e] = acc[e];
        out_eidx[tok] = (float)mi;
        eidx_i[tok] = mi;
        probs[tok] = 1.f / se;
        int pos = atomicAdd(&counts[mi], 1);
        bucket[mi * T_TOK + pos] = tok;
    }
}

// ---------------- Compact ----------------
__global__ void k_compact(const int* __restrict__ counts, int* __restrict__ offsets,
                          const int* __restrict__ bucket, int* __restrict__ sorted)
{
    __shared__ int soff[NE + 1];
    if (threadIdx.x == 0) {
        int s = 0;
        for (int e = 0; e < NE; e++) { soff[e] = s; s += counts[e]; }
        soff[NE] = s;
        for (int e = 0; e <= NE; e++) offsets[e] = soff[e];
    }
    __syncthreads();
    for (int e = 0; e < NE; e++) {
        int c = counts[e], o = soff[e];
        for (int i = threadIdx.x; i < c; i += blockDim.x)
            sorted[o + i] = bucket[e * T_TOK + i];
    }
}

// ---------------- x -> bf16 (unsorted) ----------------
__global__ __launch_bounds__(256) void k_xconv(
    const float* __restrict__ x, unsigned short* __restrict__ Xb)
{
    int g0 = (blockIdx.x * 256 + threadIdx.x) * 8;
    if (g0 >= T_TOK * DIM) return;
    f32x4 a = *(const f32x4*)(x + g0);
    f32x4 b = *(const f32x4*)(x + g0 + 4);
    *(bf16x8*)(Xb + g0) = pack8(a, b);
}

// ---------------- transpose+convert: in[R][C] f32 -> out[C][R] bf16, per expert ----------------
__global__ __launch_bounds__(256) void k_tconv(
    const float* __restrict__ in, unsigned short* __restrict__ out, int R, int C)
{
    const size_t es = (size_t)R * C;
    in  += blockIdx.z * es;
    out += blockIdx.z * es;
    const int c0 = blockIdx.x * 64, r0 = blockIdx.y * 64;
    __shared__ unsigned short t[64][72];
    const int tr = threadIdx.x >> 2, tc = (threadIdx.x & 3) * 16;
    const float* src = in + (size_t)(r0 + tr) * C + c0 + tc;
    f32x4 v0 = *(const f32x4*)(src);
    f32x4 v1 = *(const f32x4*)(src + 4);
    f32x4 v2 = *(const f32x4*)(src + 8);
    f32x4 v3 = *(const f32x4*)(src + 12);
    #pragma unroll
    for (int j = 0; j < 4; j++) {
        t[tc + j][tr]      = f2bf(v0[j]);
        t[tc + 4 + j][tr]  = f2bf(v1[j]);
        t[tc + 8 + j][tr]  = f2bf(v2[j]);
        t[tc + 12 + j][tr] = f2bf(v3[j]);
    }
    __syncthreads();
    const int oc = threadIdx.x >> 2, orr = (threadIdx.x & 3) * 16;
    bf16x8 o0, o1;
    #pragma unroll
    for (int j = 0; j < 8; j++) { o0[j] = t[oc][orr + j]; o1[j] = t[oc][orr + 8 + j]; }
    unsigned short* dst = out + (size_t)(c0 + oc) * R + r0 + orr;
    *(bf16x8*)(dst)     = o0;
    *(bf16x8*)(dst + 8) = o1;
}

// ---------------- init: out = b2[e]*prob (bias term of split-K accumulation) ----------------
__global__ __launch_bounds__(256) void k_init(
    const float* __restrict__ b2, const int* __restrict__ eidx,
    const float* __restrict__ probs, float* __restrict__ outh)
{
    int tok = blockIdx.x;
    int e = eidx[tok];
    float p = probs[tok];
    const float* br = b2 + e * DIM;
    for (int d = threadIdx.x; d < DIM; d += 256)
        outh[(size_t)tok * DIM + d] = br[d] * p;
}

// ---------------- GEMM1: H = relu(X[sorted] @ w1t[e]^T + b1), 128x128, BK=32, async LDS ----------------
__global__ __launch_bounds__(256, 3) void k_gemm1(
    const unsigned short* __restrict__ Xb, const unsigned short* __restrict__ wt1,
    const float* __restrict__ b1, const int* __restrict__ sorted,
    const int* __restrict__ counts, const int* __restrict__ offsets,
    unsigned short* __restrict__ Hbuf)
{
    const int e  = blockIdx.y >> 5;
    const int ti = blockIdx.y & 31;
    const int cnt = counts[e];
    if (ti * 128 >= cnt) return;
    const int n0 = blockIdx.x * 128;
    const int off = offsets[e];
    const int rbase = ti * 128;
    const int tid = threadIdx.x, lane = tid & 63, wave = tid >> 6;
    const int wm = wave >> 1, wn = wave & 1;

    __shared__ unsigned short As[128][32];   // no pad: global_load_lds needs contiguity
    __shared__ unsigned short Bs[128][32];

    const int lr = lane >> 2;          // row within 16-row chunk
    const int ls = (lane & 3) * 8;     // bf16 col offset (16B segs)

    int r0 = rbase + wave * 32 + lr;        if (r0 >= cnt) r0 = rbase;
    int r1 = rbase + wave * 32 + 16 + lr;   if (r1 >= cnt) r1 = rbase;
    const unsigned short* aP0 = Xb + (size_t)sorted[off + r0] * DIM + ls;   // fused gather
    const unsigned short* aP1 = Xb + (size_t)sorted[off + r1] * DIM + ls;
    const unsigned short* wB  = wt1 + (size_t)e * FF * DIM;                 // [FF][DIM]
    const unsigned short* bP0 = wB + (size_t)(n0 + wave * 32 + lr) * DIM + ls;
    const unsigned short* bP1 = wB + (size_t)(n0 + wave * 32 + 16 + lr) * DIM + ls;
    unsigned short* lA0 = &As[wave * 32][0];
    unsigned short* lA1 = &As[wave * 32 + 16][0];
    unsigned short* lB0 = &Bs[wave * 32][0];
    unsigned short* lB1 = &Bs[wave * 32 + 16][0];

    f32x4 acc[4][4];
    #pragma unroll
    for (int i = 0; i < 4; i++)
        #pragma unroll
        for (int j = 0; j < 4; j++) acc[i][j] = (f32x4)0.f;

    const int lrow = lane & 15, kq = lane >> 4;

    for (int k0 = 0; k0 < DIM; k0 += 32) {
        __syncthreads();
        g2l16(aP0 + k0, lA0);
        g2l16(aP1 + k0, lA1);
        g2l16(bP0 + k0, lB0);
        g2l16(bP1 + k0, lB1);
        __syncthreads();     // compiler drains vmcnt before s_barrier
        bf16x8 af[4], bfv[4];
        #pragma unroll
        for (int i = 0; i < 4; i++)
            af[i] = *(const bf16x8*)&As[wm * 64 + i * 16 + lrow][kq * 8];
        #pragma unroll
        for (int i = 0; i < 4; i++)
            bfv[i] = *(const bf16x8*)&Bs[wn * 64 + i * 16 + lrow][kq * 8];
        #pragma unroll
        for (int mi = 0; mi < 4; mi++)
            #pragma unroll
            for (int ni = 0; ni < 4; ni++)
                acc[mi][ni] = __builtin_amdgcn_mfma_f32_16x16x32_bf16(
                    af[mi], bfv[ni], acc[mi][ni], 0, 0, 0);
    }

    const int quad = lane >> 4;
    #pragma unroll
    for (int ni = 0; ni < 4; ni++) {
        int gn = n0 + wn * 64 + ni * 16 + lrow;
        float bias = b1[e * FF + gn];
        #pragma unroll
        for (int mi = 0; mi < 4; mi++) {
            f32x4 v = acc[mi][ni];
            #pragma unroll
            for (int r = 0; r < 4; r++) {
                int ml = rbase + wm * 64 + mi * 16 + quad * 4 + r;
                if (ml < cnt) {
                    float h = v[r] + bias; h = h > 0.f ? h : 0.f;
                    Hbuf[(size_t)(off + ml) * FF + gn] = f2bf(h);
                }
            }
        }
    }
}

// ---------------- GEMM2: out += (H @ w2t[e]^T)*prob, 128x128, split-K x4, atomic combine ----------------
__global__ __launch_bounds__(256, 3) void k_gemm2(
    const unsigned short* __restrict__ Hbuf, const unsigned short* __restrict__ wt2,
    const int* __restrict__ sorted, const int* __restrict__ counts,
    const int* __restrict__ offsets, const float* __restrict__ probs,
    float* __restrict__ outh)
{
    const int e  = blockIdx.y >> 5;
    const int ti = blockIdx.y & 31;
    const int cnt = counts[e];
    if (ti * 128 >= cnt) return;
    const int n0 = blockIdx.x * 128;          // N=768 -> 6 tiles
    const int kc = blockIdx.z;                // K chunk of 768
    const int off = offsets[e];
    const int rbase = ti * 128;
    const int tid = threadIdx.x, lane = tid & 63, wave = tid >> 6;
    const int wm = wave >> 1, wn = wave & 1;

    __shared__ unsigned short As[128][32];
    __shared__ unsigned short Bs[128][32];
    __shared__ int   s_tok[128];
    __shared__ float s_prob[128];

    if (tid < 128) {
        int rr = rbase + tid; if (rr >= cnt) rr = rbase;
        int tk = sorted[off + rr];
        s_tok[tid]  = tk;
        s_prob[tid] = probs[tk];
    }

    const int lr = lane >> 2, ls = (lane & 3) * 8;
    int r0 = rbase + wave * 32 + lr;        if (r0 >= cnt) r0 = rbase;
    int r1 = rbase + wave * 32 + 16 + lr;   if (r1 >= cnt) r1 = rbase;
    const unsigned short* aP0 = Hbuf + (size_t)(off + r0) * FF + kc * 768 + ls;
    const unsigned short* aP1 = Hbuf + (size_t)(off + r1) * FF + kc * 768 + ls;
    const unsigned short* wB  = wt2 + (size_t)e * DIM * FF;                 // [DIM][FF]
    const unsigned short* bP0 = wB + (size_t)(n0 + wave * 32 + lr) * FF + kc * 768 + ls;
    const unsigned short* bP1 = wB + (size_t)(n0 + wave * 32 + 16 + lr) * FF + kc * 768 + ls;
    unsigned short* lA0 = &As[wave * 32][0];
    unsigned short* lA1 = &As[wave * 32 + 16][0];
    unsigned short* lB0 = &Bs[wave * 32][0];
    unsigned short* lB1 = &Bs[wave * 32 + 16][0];

    f32x4 acc[4][4];
    #pragma unroll
    for (int i = 0; i < 4; i++)
        #pragma unroll
        for (int j = 0; j < 4; j++) acc[i][j] = (f32x4)0.f;

    const int lrow = lane & 15, kq = lane >> 4;

    for (int k0 = 0; k0 < 768; k0 += 32) {
        __syncthreads();
        g2l16(aP0 + k0, lA0);
        g2l16(aP1 + k0, lA1);
        g2l16(bP0 + k0, lB0);
        g2l16(bP1 + k0, lB1);
        __syncthreads();
        bf16x8 af[4], bfv[4];
        #pragma unroll
        for (int i = 0; i < 4; i++)
            af[i] = *(const bf16x8*)&As[wm * 64 + i * 16 + lrow][kq * 8];
        #pragma unroll
        for (int i = 0; i < 4; i++)
            bfv[i] = *(const bf16x8*)&Bs[wn * 64 + i * 16 + lrow][kq * 8];
        #pragma unroll
        for (int mi = 0; mi < 4; mi++)
            #pragma unroll
            for (int ni = 0; ni < 4; ni++)
                acc[mi][ni] = __builtin_amdgcn_mfma_f32_16x16x32_bf16(
                    af[mi], bfv[ni], acc[mi][ni], 0, 0, 0);
    }

    const int quad = lane >> 4;
    #pragma unroll
    for (int ni = 0; ni < 4; ni++) {
        int gn = n0 + wn * 64 + ni * 16 + lrow;
        #pragma unroll
        for (int mi = 0; mi < 4; mi++) {
            f32x4 v = acc[mi][ni];
            #pragma unroll
            for (int r = 0; r < 4; r++) {
                int mloc = wm * 64 + mi * 16 + quad * 4 + r;
                if (rbase + mloc < cnt) {
                    atomicAdd(&outh[(size_t)s_tok[mloc] * DIM + gn], v[r] * s_prob[mloc]);
                }
            }
        }
    }
}

// ================= Fallback path (R2 kernels, used only if ws too small) =================
__global__ __launch_bounds__(256) void k_gather_fb(
    const float* __restrict__ x, const int* __restrict__ sorted,
    unsigned short* __restrict__ Xg)
{
    int g0 = (blockIdx.x * 256 + threadIdx.x) * 8;
    if (g0 >= T_TOK * DIM) return;
    int row = g0 / DIM, col = g0 - row * DIM;
    const float* src = x + (size_t)sorted[row] * DIM + col;
    f32x4 a = *(const f32x4*)(src);
    f32x4 b = *(const f32x4*)(src + 4);
    *(bf16x8*)(Xg + (size_t)row * DIM + col) = pack8(a, b);
}

__global__ __launch_bounds__(256, 3) void k_gemm1_fb(
    const unsigned short* __restrict__ Xg, const float* __restrict__ w1,
    const float* __restrict__ b1, const int* __restrict__ counts,
    const int* __restrict__ offsets, unsigned short* __restrict__ Hbuf)
{
    const int e   = blockIdx.y >> 5;
    const int ti  = blockIdx.y & 31;
    const int cnt = counts[e];
    if (ti * 128 >= cnt) return;
    const int n0    = blockIdx.x * 128;
    const int off   = offsets[e];
    const int rbase = ti * 128;
    const int rmax  = cnt - rbase - 1;
    const int tid   = threadIdx.x;
    const int lane  = tid & 63;
    const int wave  = tid >> 6;
    const int wm = wave >> 1, wn = wave & 1;
    __shared__ unsigned short As[128][72];
    __shared__ unsigned short Bs[128][72];
    const float* w1e = w1 + (size_t)e * DIM * FF;
    f32x4 acc[4][4];
    #pragma unroll
    for (int i = 0; i < 4; i++)
        #pragma unroll
        for (int j = 0; j < 4; j++) acc[i][j] = (f32x4)0.f;
    const int arow = tid >> 1, aseg = tid & 1;
    const int are  = (arow <= rmax) ? arow : 0;
    const unsigned short* abase = Xg + (size_t)(off + rbase + are) * DIM + aseg * 32;
    const int kb = tid >> 5, nb = tid & 31;
    const float* bbase = w1e + (size_t)kb * 8 * FF + n0 + nb * 4;
    bf16x8 aR[4];
    f32x4  bR[8];
    #pragma unroll
    for (int j = 0; j < 4; j++) aR[j] = *(const bf16x8*)(abase + j * 8);
    #pragma unroll
    for (int r = 0; r < 8; r++) bR[r] = *(const f32x4*)(bbase + (size_t)r * FF);
    const int lrow = lane & 15, kq = lane >> 4;
    for (int it = 0; it < DIM / 64; ++it) {
        __syncthreads();
        #pragma unroll
        for (int j = 0; j < 4; j++)
            *(bf16x8*)&As[arow][aseg * 32 + j * 8] = aR[j];
        #pragma unroll
        for (int j = 0; j < 4; j++) {
            bf16x8 c;
            #pragma unroll
            for (int r = 0; r < 8; r++) c[r] = (short)f2bf(bR[r][j]);
            *(bf16x8*)&Bs[nb * 4 + j][kb * 8] = c;
        }
        __syncthreads();
        if (it + 1 < DIM / 64) {
            const unsigned short* an = abase + (it + 1) * 64;
            #pragma unroll
            for (int j = 0; j < 4; j++) aR[j] = *(const bf16x8*)(an + j * 8);
            const float* bn = bbase + (size_t)(it + 1) * 64 * FF;
            #pragma unroll
            for (int r = 0; r < 8; r++) bR[r] = *(const f32x4*)(bn + (size_t)r * FF);
        }
        #pragma unroll
        for (int ks = 0; ks < 2; ks++) {
            bf16x8 af[4], bfr[4];
            #pragma unroll
            for (int i = 0; i < 4; i++)
                af[i] = *(const bf16x8*)&As[wm * 64 + i * 16 + lrow][ks * 32 + kq * 8];
            #pragma unroll
            for (int i = 0; i < 4; i++)
                bfr[i] = *(const bf16x8*)&Bs[wn * 64 + i * 16 + lrow][ks * 32 + kq * 8];
            #pragma unroll
            for (int mi = 0; mi < 4; mi++)
                #pragma unroll
                for (int ni = 0; ni < 4; ni++)
                    acc[mi][ni] = __builtin_amdgcn_mfma_f32_16x16x32_bf16(
                        af[mi], bfr[ni], acc[mi][ni], 0, 0, 0);
        }
    }
    const int quad = lane >> 4;
    #pragma unroll
    for (int ni = 0; ni < 4; ni++) {
        int gn = n0 + wn * 64 + ni * 16 + lrow;
        float bias = b1[e * FF + gn];
        #pragma unroll
        for (int mi = 0; mi < 4; mi++) {
            f32x4 v = acc[mi][ni];
            #pragma unroll
            for (int r = 0; r < 4; r++) {
                int ml = wm * 64 + mi * 16 + quad * 4 + r;
                if (rbase + ml < cnt) {
                    float h = v[r] + bias;
                    h = h > 0.f ? h : 0.f;
                    Hbuf[(size_t)(off + rbase + ml) * FF + gn] = f2bf(h);
                }
            }
        }
    }
}

__global__ __launch_bounds__(256, 4) void k_gemm2_fb(
    const unsigned short* __restrict__ Hbuf, const float* __restrict__ w2,
    const float* __restrict__ b2, const int* __restrict__ sorted,
    const int* __restrict__ counts, const int* __restrict__ offsets,
    const float* __restrict__ probs, float* __restrict__ outh)
{
    const int e   = blockIdx.y >> 5;
    const int ti  = blockIdx.y & 31;
    const int cnt = counts[e];
    if (ti * 128 >= cnt) return;
    const int n0    = blockIdx.x * 64;
    const int off   = offsets[e];
    const int rbase = ti * 128;
    const int rmax  = cnt - rbase - 1;
    const int tid   = threadIdx.x;
    const int lane  = tid & 63;
    const int wave  = tid >> 6;
    const int wm = wave >> 1, wn = wave & 1;
    __shared__ unsigned short As[128][72];
    __shared__ unsigned short Bs[64][72];
    __shared__ int   s_tok[128];
    __shared__ float s_prob[128];
    if (tid < 128) {
        int r = rbase + tid;
        int tk = sorted[off + ((r < cnt) ? r : rbase)];
        s_tok[tid]  = tk;
        s_prob[tid] = probs[tk];
    }
    const float* w2e = w2 + (size_t)e * FF * DIM;
    f32x4 acc[4][2];
    #pragma unroll
    for (int i = 0; i < 4; i++)
        #pragma unroll
        for (int j = 0; j < 2; j++) acc[i][j] = (f32x4)0.f;
    const int arow = tid >> 1, aseg = tid & 1;
    const int are  = (arow <= rmax) ? arow : 0;
    const unsigned short* abase = Hbuf + (size_t)(off + rbase + are) * FF + aseg * 32;
    const int kb = tid >> 5, nb = tid & 31;
    const float* bbase = w2e + (size_t)kb * 8 * DIM + n0 + nb * 2;
    bf16x8 aR[4];
    f32x2  bR[8];
    #pragma unroll
    for (int j = 0; j < 4; j++) aR[j] = *(const bf16x8*)(abase + j * 8);
    #pragma unroll
    for (int r = 0; r < 8; r++) bR[r] = *(const f32x2*)(bbase + (size_t)r * DIM);
    const int lrow = lane & 15, kq = lane >> 4;
    for (int it = 0; it < FF / 64; ++it) {
        __syncthreads();
        #pragma unroll
        for (int j = 0; j < 4; j++)
            *(bf16x8*)&As[arow][aseg * 32 + j * 8] = aR[j];
        {
            bf16x8 c0, c1;
            #pragma unroll
            for (int r = 0; r < 8; r++) { c0[r] = (short)f2bf(bR[r][0]); c1[r] = (short)f2bf(bR[r][1]); }
            *(bf16x8*)&Bs[nb * 2 + 0][kb * 8] = c0;
            *(bf16x8*)&Bs[nb * 2 + 1][kb * 8] = c1;
        }
        __syncthreads();
        if (it + 1 < FF / 64) {
            const unsigned short* an = abase + (it + 1) * 64;
            #pragma unroll
            for (int j = 0; j < 4; j++) aR[j] = *(const bf16x8*)(an + j * 8);
            const float* bn = bbase + (size_t)(it + 1) * 64 * DIM;
            #pragma unroll
            for (int r = 0; r < 8; r++) bR[r] = *(const f32x2*)(bn + (size_t)r * DIM);
        }
        #pragma unroll
        for (int ks = 0; ks < 2; ks++) {
            bf16x8 af[4], bfr[2];
            #pragma unroll
            for (int i = 0; i < 4; i++)
                af[i] = *(const bf16x8*)&As[wm * 64 + i * 16 + lrow][ks * 32 + kq * 8];
            #pragma unroll
            for (int i = 0; i < 2; i++)
                bfr[i] = *(const bf16x8*)&Bs[wn * 32 + i * 16 + lrow][ks * 32 + kq * 8];
            #pragma unroll
            for (int mi = 0; mi < 4; mi++)
                #pragma unroll
                for (int ni = 0; ni < 2; ni++)
                    acc[mi][ni] = __builtin_amdgcn_mfma_f32_16x16x32_bf16(
                        af[mi], bfr[ni], acc[mi][ni], 0, 0, 0);
        }
    }
    const int quad = lane >> 4;
    #pragma unroll
    for (int ni = 0; ni < 2; ni++) {
        int gn = n0 + wn * 32 + ni * 16 + lrow;
        float bias = b2[e * DIM + gn];
        #pragma unroll
        for (int mi = 0; mi < 4; mi++) {
            f32x4 v = acc[mi][ni];
            #pragma unroll
            for (int r = 0; r < 4; r++) {
                int ml = wm * 64 + mi * 16 + quad * 4 + r;
                if (rbase + ml < cnt) {
                    outh[(size_t)s_tok[ml] * DIM + gn] = (v[r] + bias) * s_prob[ml];
                }
            }
        }
    }
}

extern "C" void kernel_launch(void* const* d_in, const int* in_sizes, int n_in,
                              void* d_out, int out_size, void* d_ws, size_t ws_size,
                              hipStream_t stream) {
    (void)in_sizes; (void)n_in; (void)out_size;
    const float* x  = (const float*)d_in[0];
    const float* wr = (const float*)d_in[1];
    const float* w1 = (const float*)d_in[2];
    const float* b1 = (const float*)d_in[3];
    const float* w2 = (const float*)d_in[4];
    const float* b2 = (const float*)d_in[5];

    float* out_hidden = (float*)d_out;                        // [T, D]
    float* out_logits = out_hidden + (size_t)T_TOK * DIM;     // [T, E]
    float* out_eidx   = out_logits + (size_t)T_TOK * NE;      // [T]

    char* ws = (char*)d_ws;
    int*   counts  = (int*)(ws + 0);
    int*   offsets = (int*)(ws + 64);
    float* probs   = (float*)(ws + 128);
    int*   eidx_i  = (int*)(ws + 16512);
    int*   sorted  = (int*)(ws + 32896);
    int*   bucket  = (int*)(ws + 49280);
    unsigned short* Xb   = (unsigned short*)(ws + 180352);    // T*DIM bf16
    unsigned short* Hbuf = (unsigned short*)(ws + 6471808);   // T*FF bf16
    unsigned short* wt1  = (unsigned short*)(ws + 31637632);  // E*FF*DIM bf16 [e][f][d]
    unsigned short* wt2  = (unsigned short*)(ws + 69386368);  // E*DIM*FF bf16 [e][d][f]
    const size_t NEED = 107135104;

    hipMemsetAsync(counts, 0, 32, stream);
    k_router<<<dim3(T_TOK / 4), dim3(256), 0, stream>>>(
        x, wr, out_logits, out_eidx, probs, eidx_i, counts, bucket);
    k_compact<<<dim3(1), dim3(256), 0, stream>>>(counts, offsets, bucket, sorted);

    if (ws_size >= NEED) {
        k_xconv<<<dim3(T_TOK * DIM / 8 / 256), dim3(256), 0, stream>>>(x, Xb);
        k_tconv<<<dim3(FF / 64, DIM / 64, NE), dim3(256), 0, stream>>>(w1, wt1, DIM, FF);
        k_tconv<<<dim3(DIM / 64, FF / 64, NE), dim3(256), 0, stream>>>(w2, wt2, FF, DIM);
        k_init<<<dim3(T_TOK), dim3(256), 0, stream>>>(b2, eidx_i, probs, out_hidden);
        k_gemm1<<<dim3(FF / 128, NE * 32), dim3(256), 0, stream>>>(
            Xb, wt1, b1, sorted, counts, offsets, Hbuf);
        k_gemm2<<<dim3(DIM / 128, NE * 32, 4), dim3(256), 0, stream>>>(
            Hbuf, wt2, sorted, counts, offsets, probs, out_hidden);
    } else {
        k_gather_fb<<<dim3(T_TOK * DIM / 8 / 256), dim3(256), 0, stream>>>(x, sorted, Xb);
        k_gemm1_fb<<<dim3(FF / 128, NE * 32), dim3(256), 0, stream>>>(
            Xb, w1, b1, counts, offsets, Hbuf);
        k_gemm2_fb<<<dim3(DIM / 64, NE * 32), dim3(256), 0, stream>>>(
            Hbuf, w2, b2, sorted, counts, offsets, probs, out_hidden);
    }
}